// Round 3
// baseline (1175.164 us; speedup 1.0000x reference)
//
#include <hip/hip_runtime.h>
#include <stdint.h>

#define HDIM 128
#define NGRID 262144
#define NEDGE 524288

typedef __attribute__((ext_vector_type(8))) short short8;
typedef __attribute__((ext_vector_type(16))) float f32x16;

static __device__ __forceinline__ unsigned int f2bf_u(float f) {
  union { float f; uint32_t u; } v; v.f = f;
  uint32_t u = v.u;
  u += 0x7fffu + ((u >> 16) & 1u);
  return u >> 16;
}
static __device__ __forceinline__ unsigned short f2bf(float f) { return (unsigned short)f2bf_u(f); }
static __device__ __forceinline__ unsigned int pack2bf(float a, float b) {
  return f2bf_u(a) | (f2bf_u(b) << 16);
}
static __device__ __forceinline__ short8 cvt8(const float* p) {
  float4 f0 = *(const float4*)p;
  float4 f1 = *(const float4*)(p + 4);
  short8 r;
  r[0] = (short)f2bf_u(f0.x); r[1] = (short)f2bf_u(f0.y);
  r[2] = (short)f2bf_u(f0.z); r[3] = (short)f2bf_u(f0.w);
  r[4] = (short)f2bf_u(f1.x); r[5] = (short)f2bf_u(f1.y);
  r[6] = (short)f2bf_u(f1.z); r[7] = (short)f2bf_u(f1.w);
  return r;
}
static __device__ __forceinline__ void atom_pk_bf16(unsigned short* p, unsigned int v) {
  asm volatile("global_atomic_pk_add_bf16 %0, %1, off" :: "v"(p), "v"(v) : "memory");
}

union U8 { unsigned int u[4]; short8 s; };

// ---- pack weights: fp32 [K][128] -> bf16 transposed, XOR-swizzled for LDS b128 reads ----
// dst byte = row*S + ((2k) ^ ((row&7)<<4)); all strides are multiples of 256 so bits 0-7 of
// row*S are zero and the XOR is confined to the k-offset.
__global__ void pack_weights(const float* __restrict__ eW1, const float* __restrict__ eW2,
                             const float* __restrict__ nW1, const float* __restrict__ nW2,
                             unsigned char* __restrict__ wbase)
{
  int i = blockIdx.x * 256 + threadIdx.x;
  if (i < 49152) {                 // eW1T [128][384] stride 768
    int row = i / 384, k = i % 384;
    int db = row * 768 + ((2 * k) ^ ((row & 7) << 4));
    *(unsigned short*)(wbase + db) = f2bf(eW1[(size_t)k * 128 + row]);
  } else if (i < 65536) {          // eW2T [128][128] stride 256 @ +98304
    int j = i - 49152; int row = j / 128, k = j % 128;
    int db = row * 256 + ((2 * k) ^ ((row & 7) << 4));
    *(unsigned short*)(wbase + 98304 + db) = f2bf(eW2[(size_t)k * 128 + row]);
  } else if (i < 98304) {          // nW1T [128][256] stride 512 @ +131072
    int j = i - 65536; int row = j / 256, k = j % 256;
    int db = row * 512 + ((2 * k) ^ ((row & 7) << 4));
    *(unsigned short*)(wbase + 131072 + db) = f2bf(nW1[(size_t)k * 128 + row]);
  } else if (i < 114688) {         // nW2T [128][128] stride 256 @ +196608
    int j = i - 98304; int row = j / 128, k = j % 128;
    int db = row * 256 + ((2 * k) ^ ((row & 7) << 4));
    *(unsigned short*)(wbase + 196608 + db) = f2bf(nW2[(size_t)k * 128 + row]);
  }
}

// ---------------- edge kernel: swapped-operand MFMA, weights LDS-resident ----------------
// Per wave: 2 tiles x 32 edges. D1[h1col][edge] = W1T x xe^T ; h1 stays in registers
// (lane&31 = edge). GEMM2 B-frags built via one shfl_xor(32) pair-exchange per window.
template<bool BF16AGG>
__global__ __launch_bounds__(512, 2)
void edge_kernel(const float* __restrict__ ef, const float* __restrict__ gridf,
                 const float* __restrict__ mesh,
                 const unsigned char* __restrict__ wbase,
                 const float* __restrict__ b1, const float* __restrict__ b2,
                 const float* __restrict__ lng, const float* __restrict__ lnb,
                 const int* __restrict__ src, const int* __restrict__ dst,
                 unsigned short* __restrict__ aggb, float* __restrict__ aggf)
{
  __shared__ __align__(16) unsigned char smem[131072];   // eW1T 96KB + eW2T 32KB

  const int tid = threadIdx.x;
  {
    const uint4* gsrc = (const uint4*)wbase;
    uint4* ldst = (uint4*)smem;
    #pragma unroll
    for (int i = 0; i < 16; ++i) ldst[tid + i * 512] = gsrc[tid + i * 512];
  }
  __syncthreads();

  const int wv = tid >> 6, ln = tid & 63, l31 = ln & 31, hi = ln >> 5;
  const int job = blockIdx.x * 8 + wv;
  const int swz = (l31 & 7) << 4;

  const float* rowS[2]; const float* rowD[2]; const float* rowE[2]; int dI[2];
  #pragma unroll
  for (int t = 0; t < 2; ++t) {
    int e = job * 64 + t * 32 + l31;
    int s = src[e]; int d = dst[e]; dI[t] = d;
    rowS[t] = mesh  + (size_t)s * HDIM;
    rowD[t] = gridf + (size_t)d * HDIM;
    rowE[t] = ef    + (size_t)e * HDIM;
  }

  // ---- GEMM1: K=384, 24 k-steps of 16 ----
  f32x16 acc1[8];
  #pragma unroll
  for (int i = 0; i < 8; ++i) acc1[i] = (f32x16)(0.f);

  #pragma unroll
  for (int ks = 0; ks < 24; ++ks) {
    short8 A[4];
    #pragma unroll
    for (int c = 0; c < 4; ++c) {
      int addr = (32 * c + l31) * 768 + ((32 * ks + 16 * hi) ^ swz);
      A[c] = *(const short8*)(smem + addr);
    }
    short8 Bt[2];
    #pragma unroll
    for (int t = 0; t < 2; ++t) {
      const float* base = (ks < 8) ? rowS[t] : (ks < 16) ? rowD[t] : rowE[t];
      Bt[t] = cvt8(base + (ks & 7) * 16 + hi * 8);
    }
    #pragma unroll
    for (int t = 0; t < 2; ++t)
      #pragma unroll
      for (int c = 0; c < 4; ++c)
        acc1[t * 4 + c] = __builtin_amdgcn_mfma_f32_32x32x16_bf16(A[c], Bt[t], acc1[t * 4 + c], 0, 0, 0);
  }

  // ---- per tile: silu -> GEMM2 -> LN -> residual -> atomic scatter ----
  #pragma unroll
  for (int t = 0; t < 2; ++t) {
    // silu(x + b1). h1 col for reg r of block c: 32c + (r&3) + 8*(r>>2) + 4*hi
    #pragma unroll
    for (int c = 0; c < 4; ++c) {
      #pragma unroll
      for (int q = 0; q < 4; ++q) {
        float4 b1q = *(const float4*)(b1 + 32 * c + 8 * q + 4 * hi);
        #pragma unroll
        for (int i = 0; i < 4; ++i) {
          float x = acc1[t * 4 + c][q * 4 + i] + b1q[i];
          acc1[t * 4 + c][q * 4 + i] = x / (1.f + __expf(-x));
        }
      }
    }
    // build GEMM2 B-frags: window w covers h1 cols 16w..16w+15
    U8 B2[8];
    #pragma unroll
    for (int w = 0; w < 8; ++w) {
      int c = w >> 1, h = w & 1;
      const f32x16& a = acc1[t * 4 + c];
      unsigned P1a = pack2bf(a[8 * h + 0], a[8 * h + 1]);
      unsigned P1b = pack2bf(a[8 * h + 2], a[8 * h + 3]);
      unsigned P2a = pack2bf(a[8 * h + 4], a[8 * h + 5]);
      unsigned P2b = pack2bf(a[8 * h + 6], a[8 * h + 7]);
      unsigned sA = hi ? P1a : P2a, sB = hi ? P1b : P2b;
      unsigned rA = (unsigned)__shfl_xor((int)sA, 32);
      unsigned rB = (unsigned)__shfl_xor((int)sB, 32);
      B2[w].u[0] = hi ? rA : P1a;
      B2[w].u[1] = hi ? rB : P1b;
      B2[w].u[2] = hi ? P2a : rA;
      B2[w].u[3] = hi ? P2b : rB;
    }
    // GEMM2: K=128, 8 windows
    f32x16 acc2[4];
    #pragma unroll
    for (int i = 0; i < 4; ++i) acc2[i] = (f32x16)(0.f);
    #pragma unroll
    for (int c2 = 0; c2 < 4; ++c2) {
      #pragma unroll
      for (int w = 0; w < 8; ++w) {
        int addr = 98304 + (32 * c2 + l31) * 256 + ((32 * w + 16 * hi) ^ swz);
        short8 A2 = *(const short8*)(smem + addr);
        acc2[c2] = __builtin_amdgcn_mfma_f32_32x32x16_bf16(A2, B2[w].s, acc2[c2], 0, 0, 0);
      }
    }
    // +b2, LN over 128 cols (64 in-lane + partner via shfl_xor 32)
    float vs = 0.f, vq = 0.f;
    #pragma unroll
    for (int c2 = 0; c2 < 4; ++c2) {
      #pragma unroll
      for (int q = 0; q < 4; ++q) {
        float4 b2q = *(const float4*)(b2 + 32 * c2 + 8 * q + 4 * hi);
        #pragma unroll
        for (int i = 0; i < 4; ++i) {
          float x = acc2[c2][q * 4 + i] + b2q[i];
          acc2[c2][q * 4 + i] = x;
          vs += x; vq += x * x;
        }
      }
    }
    vs += __shfl_xor(vs, 32);
    vq += __shfl_xor(vq, 32);
    float mean = vs * (1.f / 128.f);
    float rstd = rsqrtf(vq * (1.f / 128.f) - mean * mean + 1e-5f);

    #pragma unroll
    for (int c2 = 0; c2 < 4; ++c2) {
      #pragma unroll
      for (int q = 0; q < 4; ++q) {
        int colb = 32 * c2 + 8 * q + 4 * hi;
        float4 g4 = *(const float4*)(lng + colb);
        float4 bb4 = *(const float4*)(lnb + colb);
        float4 e4 = *(const float4*)(rowE[t] + colb);
        float e0 = e4.x + (acc2[c2][q * 4 + 0] - mean) * rstd * g4.x + bb4.x;
        float e1 = e4.y + (acc2[c2][q * 4 + 1] - mean) * rstd * g4.y + bb4.y;
        float e2 = e4.z + (acc2[c2][q * 4 + 2] - mean) * rstd * g4.z + bb4.z;
        float e3 = e4.w + (acc2[c2][q * 4 + 3] - mean) * rstd * g4.w + bb4.w;
        if (BF16AGG) {
          unsigned short* p = aggb + (size_t)dI[t] * HDIM + colb;
          atom_pk_bf16(p, pack2bf(e0, e1));
          atom_pk_bf16(p + 2, pack2bf(e2, e3));
        } else {
          float* p = aggf + (size_t)dI[t] * HDIM + colb;
          unsafeAtomicAdd(p + 0, e0);
          unsafeAtomicAdd(p + 1, e1);
          unsafeAtomicAdd(p + 2, e2);
          unsafeAtomicAdd(p + 3, e3);
        }
      }
    }
  }
}

// ---------------- node kernel: same swapped structure, contiguous rows, plain stores ----------------
template<bool BF16AGG>
__global__ __launch_bounds__(512, 2)
void node_kernel(const float* __restrict__ gridf,
                 const unsigned char* __restrict__ wbase,   // nW1T at 0 (stride 512), nW2T at 65536
                 const float* __restrict__ b1, const float* __restrict__ b2,
                 const float* __restrict__ lng, const float* __restrict__ lnb,
                 const unsigned short* __restrict__ aggb, const float* __restrict__ aggf,
                 float* __restrict__ out)
{
  __shared__ __align__(16) unsigned char smem[98304];

  const int tid = threadIdx.x;
  {
    const uint4* gsrc = (const uint4*)wbase;
    uint4* ldst = (uint4*)smem;
    #pragma unroll
    for (int i = 0; i < 12; ++i) ldst[tid + i * 512] = gsrc[tid + i * 512];
  }
  __syncthreads();

  const int wv = tid >> 6, ln = tid & 63, l31 = ln & 31, hi = ln >> 5;
  const int job = blockIdx.x * 8 + wv;
  const int swz = (l31 & 7) << 4;

  int nIdx[2];
  #pragma unroll
  for (int t = 0; t < 2; ++t) nIdx[t] = job * 64 + t * 32 + l31;

  // ---- GEMM1: K=256, 16 k-steps ----
  f32x16 acc1[8];
  #pragma unroll
  for (int i = 0; i < 8; ++i) acc1[i] = (f32x16)(0.f);

  #pragma unroll
  for (int ks = 0; ks < 16; ++ks) {
    short8 A[4];
    #pragma unroll
    for (int c = 0; c < 4; ++c) {
      int addr = (32 * c + l31) * 512 + ((32 * ks + 16 * hi) ^ swz);
      A[c] = *(const short8*)(smem + addr);
    }
    short8 Bt[2];
    #pragma unroll
    for (int t = 0; t < 2; ++t) {
      if (ks < 8) {
        Bt[t] = cvt8(gridf + (size_t)nIdx[t] * HDIM + ks * 16 + hi * 8);
      } else {
        if (BF16AGG) {
          Bt[t] = *(const short8*)(aggb + (size_t)nIdx[t] * HDIM + (ks - 8) * 16 + hi * 8);
        } else {
          Bt[t] = cvt8(aggf + (size_t)nIdx[t] * HDIM + (ks - 8) * 16 + hi * 8);
        }
      }
    }
    #pragma unroll
    for (int t = 0; t < 2; ++t)
      #pragma unroll
      for (int c = 0; c < 4; ++c)
        acc1[t * 4 + c] = __builtin_amdgcn_mfma_f32_32x32x16_bf16(A[c], Bt[t], acc1[t * 4 + c], 0, 0, 0);
  }

  #pragma unroll
  for (int t = 0; t < 2; ++t) {
    #pragma unroll
    for (int c = 0; c < 4; ++c) {
      #pragma unroll
      for (int q = 0; q < 4; ++q) {
        float4 b1q = *(const float4*)(b1 + 32 * c + 8 * q + 4 * hi);
        #pragma unroll
        for (int i = 0; i < 4; ++i) {
          float x = acc1[t * 4 + c][q * 4 + i] + b1q[i];
          acc1[t * 4 + c][q * 4 + i] = x / (1.f + __expf(-x));
        }
      }
    }
    U8 B2[8];
    #pragma unroll
    for (int w = 0; w < 8; ++w) {
      int c = w >> 1, h = w & 1;
      const f32x16& a = acc1[t * 4 + c];
      unsigned P1a = pack2bf(a[8 * h + 0], a[8 * h + 1]);
      unsigned P1b = pack2bf(a[8 * h + 2], a[8 * h + 3]);
      unsigned P2a = pack2bf(a[8 * h + 4], a[8 * h + 5]);
      unsigned P2b = pack2bf(a[8 * h + 6], a[8 * h + 7]);
      unsigned sA = hi ? P1a : P2a, sB = hi ? P1b : P2b;
      unsigned rA = (unsigned)__shfl_xor((int)sA, 32);
      unsigned rB = (unsigned)__shfl_xor((int)sB, 32);
      B2[w].u[0] = hi ? rA : P1a;
      B2[w].u[1] = hi ? rB : P1b;
      B2[w].u[2] = hi ? P2a : rA;
      B2[w].u[3] = hi ? P2b : rB;
    }
    f32x16 acc2[4];
    #pragma unroll
    for (int i = 0; i < 4; ++i) acc2[i] = (f32x16)(0.f);
    #pragma unroll
    for (int c2 = 0; c2 < 4; ++c2) {
      #pragma unroll
      for (int w = 0; w < 8; ++w) {
        int addr = 65536 + (32 * c2 + l31) * 256 + ((32 * w + 16 * hi) ^ swz);
        short8 A2 = *(const short8*)(smem + addr);
        acc2[c2] = __builtin_amdgcn_mfma_f32_32x32x16_bf16(A2, B2[w].s, acc2[c2], 0, 0, 0);
      }
    }
    float vs = 0.f, vq = 0.f;
    #pragma unroll
    for (int c2 = 0; c2 < 4; ++c2) {
      #pragma unroll
      for (int q = 0; q < 4; ++q) {
        float4 b2q = *(const float4*)(b2 + 32 * c2 + 8 * q + 4 * hi);
        #pragma unroll
        for (int i = 0; i < 4; ++i) {
          float x = acc2[c2][q * 4 + i] + b2q[i];
          acc2[c2][q * 4 + i] = x;
          vs += x; vq += x * x;
        }
      }
    }
    vs += __shfl_xor(vs, 32);
    vq += __shfl_xor(vq, 32);
    float mean = vs * (1.f / 128.f);
    float rstd = rsqrtf(vq * (1.f / 128.f) - mean * mean + 1e-5f);

    #pragma unroll
    for (int c2 = 0; c2 < 4; ++c2) {
      #pragma unroll
      for (int q = 0; q < 4; ++q) {
        int colb = 32 * c2 + 8 * q + 4 * hi;
        float4 g4 = *(const float4*)(lng + colb);
        float4 bb4 = *(const float4*)(lnb + colb);
        float4 gr = *(const float4*)(gridf + (size_t)nIdx[t] * HDIM + colb);
        float4 res;
        res.x = gr.x + (acc2[c2][q * 4 + 0] - mean) * rstd * g4.x + bb4.x;
        res.y = gr.y + (acc2[c2][q * 4 + 1] - mean) * rstd * g4.y + bb4.y;
        res.z = gr.z + (acc2[c2][q * 4 + 2] - mean) * rstd * g4.z + bb4.z;
        res.w = gr.w + (acc2[c2][q * 4 + 3] - mean) * rstd * g4.w + bb4.w;
        *(float4*)(out + (size_t)nIdx[t] * HDIM + colb) = res;
      }
    }
  }
}

extern "C" void kernel_launch(void* const* d_in, const int* in_sizes, int n_in,
                              void* d_out, int out_size, void* d_ws, size_t ws_size,
                              hipStream_t stream)
{
  (void)in_sizes; (void)n_in; (void)out_size;
  const float* ef   = (const float*)d_in[0];
  const float* grid = (const float*)d_in[1];
  const float* mesh = (const float*)d_in[2];
  const float* eW1  = (const float*)d_in[3];
  const float* eb1  = (const float*)d_in[4];
  const float* eW2  = (const float*)d_in[5];
  const float* eb2  = (const float*)d_in[6];
  const float* elng = (const float*)d_in[7];
  const float* elnb = (const float*)d_in[8];
  const float* nW1  = (const float*)d_in[9];
  const float* nb1  = (const float*)d_in[10];
  const float* nW2  = (const float*)d_in[11];
  const float* nb2  = (const float*)d_in[12];
  const float* nlng = (const float*)d_in[13];
  const float* nlnb = (const float*)d_in[14];
  const int* src    = (const int*)d_in[15];
  const int* dst    = (const int*)d_in[16];
  float* out = (float*)d_out;

  const size_t AGG_BYTES = (size_t)NGRID * HDIM * 2;          // 67108864
  const size_t W_BYTES   = 229376;
  bool bf16agg = ws_size >= AGG_BYTES + W_BYTES;

  unsigned char* wsb = (unsigned char*)d_ws;
  unsigned short* aggb = (unsigned short*)wsb;
  unsigned char* wbase = bf16agg ? (wsb + AGG_BYTES) : wsb;

  pack_weights<<<448, 256, 0, stream>>>(eW1, eW2, nW1, nW2, wbase);
  if (bf16agg) {
    hipMemsetAsync(aggb, 0, AGG_BYTES, stream);
    edge_kernel<true><<<1024, 512, 0, stream>>>(ef, grid, mesh, wbase,
        eb1, eb2, elng, elnb, src, dst, aggb, nullptr);
    node_kernel<true><<<512, 512, 0, stream>>>(grid, wbase + 131072,
        nb1, nb2, nlng, nlnb, aggb, nullptr, out);
  } else {
    hipMemsetAsync(out, 0, (size_t)NGRID * HDIM * sizeof(float), stream);
    edge_kernel<false><<<1024, 512, 0, stream>>>(ef, grid, mesh, wbase,
        eb1, eb2, elng, elnb, src, dst, nullptr, out);
    node_kernel<false><<<512, 512, 0, stream>>>(grid, wbase + 131072,
        nb1, nb2, nlng, nlnb, nullptr, out, out);
  }
}

// Round 4
// 859.840 us; speedup vs baseline: 1.3667x; 1.3667x over previous
//
#include <hip/hip_runtime.h>
#include <stdint.h>

#define HDIM 128
#define NGRID 262144
#define NMESH 40962
#define NEDGE 524288

typedef __attribute__((ext_vector_type(8))) short short8;
typedef __attribute__((ext_vector_type(16))) float f32x16;
typedef unsigned int u32;
typedef unsigned long long u64;

// ---- ws layout (byte offsets) ----
#define WS_COUNT   0x000000u   // u32[NGRID]        (1 MB)
#define WS_ROWPTR  0x100000u   // u32[NGRID+1]
#define WS_WLOC    0x200010u   // u32[NGRID]
#define WS_BSUM    0x300100u   // u32[256]
#define WS_SORTED  0x310000u   // u64[NEDGE]        (4 MB)
#define WS_WEIGHTS 0x800000u   // u16[114688]       (224 KB)
// weight section offsets in u16 units:
#define WE1 0u
#define WE2 49152u
#define WN1 65536u
#define WN2 98304u

static __device__ __forceinline__ u32 f2bf_u(float f) {
  union { float f; u32 u; } v; v.f = f;
  u32 u = v.u;
  u += 0x7fffu + ((u >> 16) & 1u);
  return u >> 16;
}
static __device__ __forceinline__ unsigned short f2bf(float f) { return (unsigned short)f2bf_u(f); }
static __device__ __forceinline__ u32 pack2bf(float a, float b) {
  return f2bf_u(a) | (f2bf_u(b) << 16);
}
static __device__ __forceinline__ short8 cvt8(const float* p) {
  float4 f0 = *(const float4*)p;
  float4 f1 = *(const float4*)(p + 4);
  short8 r;
  r[0] = (short)f2bf_u(f0.x); r[1] = (short)f2bf_u(f0.y);
  r[2] = (short)f2bf_u(f0.z); r[3] = (short)f2bf_u(f0.w);
  r[4] = (short)f2bf_u(f1.x); r[5] = (short)f2bf_u(f1.y);
  r[6] = (short)f2bf_u(f1.z); r[7] = (short)f2bf_u(f1.w);
  return r;
}

// ---- pack weights frag-major: frag (w,ks) for 32x32x16, lane-contiguous 16B ----
__global__ void pack_weights(const float* __restrict__ eW1, const float* __restrict__ eW2,
                             const float* __restrict__ nW1, const float* __restrict__ nW2,
                             unsigned short* __restrict__ wp)
{
  int i = blockIdx.x * 256 + threadIdx.x;
  const float* W; int KS; u32 base; int j;
  if (i < 49152)       { W = eW1; KS = 24; base = WE1; j = i; }
  else if (i < 65536)  { W = eW2; KS = 8;  base = WE2; j = i - 49152; }
  else if (i < 98304)  { W = nW1; KS = 16; base = WN1; j = i - 65536; }
  else if (i < 114688) { W = nW2; KS = 8;  base = WN2; j = i - 98304; }
  else return;
  int ii = j & 7, l = (j >> 3) & 63, frag = j >> 9;
  int ks = frag % KS, w = frag / KS;
  int row = w * 32 + (l & 31);
  int k = ks * 16 + (l >> 5) * 8 + ii;
  wp[base + j] = f2bf(W[(size_t)k * 128 + row]);
}

__global__ void hist_k(const int* __restrict__ dst, u32* __restrict__ cnt) {
  int e = blockIdx.x * 256 + threadIdx.x;
  atomicAdd(&cnt[dst[e]], 1u);
}

__global__ void scan1(const u32* __restrict__ cnt, u32* __restrict__ rp, u32* __restrict__ bsum) {
  int t = threadIdx.x, b = blockIdx.x;
  int i0 = b * 1024 + t * 4;
  uint4 v = *(const uint4*)(cnt + i0);
  u32 s = v.x + v.y + v.z + v.w;
  u32 sc = s;
  #pragma unroll
  for (int d = 1; d < 64; d <<= 1) {
    u32 n = (u32)__shfl_up((int)sc, d);
    if ((t & 63) >= d) sc += n;
  }
  __shared__ u32 wsum[4];
  if ((t & 63) == 63) wsum[t >> 6] = sc;
  __syncthreads();
  u32 woff = 0;
  for (int w = 0; w < (t >> 6); ++w) woff += wsum[w];
  u32 ex = woff + sc - s;
  rp[i0] = ex; rp[i0 + 1] = ex + v.x; rp[i0 + 2] = ex + v.x + v.y; rp[i0 + 3] = ex + v.x + v.y + v.z;
  if (t == 255) bsum[b] = woff + sc;
}

__global__ void scan2(u32* __restrict__ bsum) {
  int t = threadIdx.x;
  u32 s = bsum[t];
  u32 sc = s;
  #pragma unroll
  for (int d = 1; d < 64; d <<= 1) {
    u32 n = (u32)__shfl_up((int)sc, d);
    if ((t & 63) >= d) sc += n;
  }
  __shared__ u32 wsum[4];
  if ((t & 63) == 63) wsum[t >> 6] = sc;
  __syncthreads();
  u32 woff = 0;
  for (int w = 0; w < (t >> 6); ++w) woff += wsum[w];
  bsum[t] = woff + sc - s;
}

__global__ void scan3(u32* __restrict__ rp, u32* __restrict__ wloc, const u32* __restrict__ bsum) {
  int t = threadIdx.x, b = blockIdx.x;
  int i0 = b * 1024 + t * 4;
  u32 off = bsum[b];
  #pragma unroll
  for (int j = 0; j < 4; ++j) { u32 vv = rp[i0 + j] + off; rp[i0 + j] = vv; wloc[i0 + j] = vv; }
  if (b == 0 && t == 0) rp[NGRID] = NEDGE;
}

__global__ void scatter_k(const int* __restrict__ src, const int* __restrict__ dst,
                          u32* __restrict__ wloc, u64* __restrict__ sorted) {
  int e = blockIdx.x * 256 + threadIdx.x;
  int d = dst[e];
  u32 pos = atomicAdd(&wloc[d], 1u);
  sorted[pos] = (u64)(u32)src[e] | ((u64)(u32)d << 16) | ((u64)(u32)e << 34);
}

// ---- fused: per block = 32 grid nodes + their sorted edges. No global atomics. ----
__global__ __launch_bounds__(256, 3)
void fused_kernel(const float* __restrict__ ef, const float* __restrict__ gridf,
                  const float* __restrict__ mesh,
                  const unsigned short* __restrict__ wp,
                  const float* __restrict__ eb1, const float* __restrict__ eb2,
                  const float* __restrict__ elng, const float* __restrict__ elnb,
                  const float* __restrict__ nb1, const float* __restrict__ nb2,
                  const float* __restrict__ nlng, const float* __restrict__ nlnb,
                  const u32* __restrict__ rowptr, const u64* __restrict__ sorted,
                  float* __restrict__ out)
{
  __shared__ unsigned short xeLDS[32 * 384];   // 24 KB, XOR-swizzled rows
  __shared__ unsigned short h1LDS[32 * 128];   // 8 KB, XOR-swizzled rows
  __shared__ float aggLDS[32 * 129];           // 16.5 KB, stride-129 conflict-free
  __shared__ float statsLDS[4][32][2];
  __shared__ u32 srE[32], dlE[32], oeE[32];

  const int tid = threadIdx.x;
  const int wv = tid >> 6, ln = tid & 63, l31 = ln & 63 & 31, hi = ln >> 5;
  const int n0 = blockIdx.x * 32;
  const int rs = (int)rowptr[n0], re = (int)rowptr[n0 + 32];
  const int swzE = (l31 & 15) << 3;   // u16-unit swizzle for row l31

  for (int i = tid; i < 32 * 129; i += 256) aggLDS[i] = 0.f;
  __syncthreads();

  const short8* w1p = (const short8*)(wp + WE1) + wv * 24 * 64 + ln;
  const short8* w2p = (const short8*)(wp + WE2) + wv * 8 * 64 + ln;

  for (int base = rs; base < re; base += 32) {
    if (tid < 32) {
      int p = base + tid; if (p >= re) p = re - 1;
      u64 v = sorted[p];
      srE[tid] = (u32)(v & 0xffffu);
      dlE[tid] = (u32)((v >> 16) & 0x3ffffu) - (u32)n0;
      oeE[tid] = (u32)(v >> 34);
    }
    __syncthreads();
    // stage xe = [mesh(src) | grid(dst) | ef] as bf16, swizzled
    for (int j = tid; j < 32 * 48; j += 256) {
      int e = j / 48, u = j - e * 48;
      int col0 = u * 8;
      const float* bp;
      if (col0 < 128)      bp = mesh  + (size_t)srE[e] * HDIM + col0;
      else if (col0 < 256) bp = gridf + (size_t)(n0 + dlE[e]) * HDIM + (col0 - 128);
      else                 bp = ef    + (size_t)oeE[e] * HDIM + (col0 - 256);
      short8 v = cvt8(bp);
      *(short8*)(xeLDS + e * 384 + (col0 ^ ((e & 15) << 3))) = v;
    }
    __syncthreads();

    // GEMM1: h1[32 cols(wave) x 32 edges], K=384
    f32x16 acc1 = (f32x16)(0.f);
    #pragma unroll 8
    for (int ks = 0; ks < 24; ++ks) {
      short8 A = w1p[ks * 64];
      short8 B = *(const short8*)(xeLDS + l31 * 384 + ((ks * 16 + hi * 8) ^ swzE));
      acc1 = __builtin_amdgcn_mfma_f32_32x32x16_bf16(A, B, acc1, 0, 0, 0);
    }
    // silu(x+b1) -> h1LDS (packed pair writes)
    #pragma unroll
    for (int q = 0; q < 4; ++q) {
      #pragma unroll
      for (int m = 0; m < 2; ++m) {
        int r0 = q * 4 + m * 2;
        int col = 32 * wv + 8 * q + 4 * hi + 2 * m;
        float2 bb = *(const float2*)(eb1 + col);
        float x0 = acc1[r0] + bb.x, x1 = acc1[r0 + 1] + bb.y;
        x0 = x0 / (1.f + __expf(-x0));
        x1 = x1 / (1.f + __expf(-x1));
        *(u32*)(h1LDS + (l31 * 128 + (col ^ swzE))) = pack2bf(x0, x1);
      }
    }
    __syncthreads();

    // GEMM2: he[32 outcols(wave) x 32 edges], K=128
    f32x16 acc2 = (f32x16)(0.f);
    #pragma unroll
    for (int ks = 0; ks < 8; ++ks) {
      short8 A = w2p[ks * 64];
      short8 B = *(const short8*)(h1LDS + l31 * 128 + ((ks * 16 + hi * 8) ^ swzE));
      acc2 = __builtin_amdgcn_mfma_f32_32x32x16_bf16(A, B, acc2, 0, 0, 0);
    }
    // +b2, LN stats
    float vs = 0.f, vq = 0.f;
    #pragma unroll
    for (int r = 0; r < 16; ++r) {
      int col = 32 * wv + (r & 3) + 8 * (r >> 2) + 4 * hi;
      float x = acc2[r] + eb2[col];
      acc2[r] = x; vs += x; vq += x * x;
    }
    vs += __shfl_xor(vs, 32); vq += __shfl_xor(vq, 32);
    if (ln < 32) { statsLDS[wv][l31][0] = vs; statsLDS[wv][l31][1] = vq; }
    __syncthreads();
    float vsT = 0.f, vqT = 0.f;
    #pragma unroll
    for (int w2 = 0; w2 < 4; ++w2) { vsT += statsLDS[w2][l31][0]; vqT += statsLDS[w2][l31][1]; }
    float mean = vsT * (1.f / 128.f);
    float rstd = rsqrtf(vqT * (1.f / 128.f) - mean * mean + 1e-5f);
    bool valid = (base + l31) < re;
    int dl = (int)dlE[l31];
    u32 oe = oeE[l31];
    #pragma unroll
    for (int r = 0; r < 16; ++r) {
      int col = 32 * wv + (r & 3) + 8 * (r >> 2) + 4 * hi;
      float val = (acc2[r] - mean) * rstd * elng[col] + elnb[col] + ef[(size_t)oe * HDIM + col];
      if (valid) atomicAdd(&aggLDS[dl * 129 + col], val);
    }
    __syncthreads();
  }

  // ---- node part: xn = [grid | agg], MLP + LN + residual ----
  const short8* nw1p = (const short8*)(wp + WN1) + wv * 16 * 64 + ln;
  const short8* nw2p = (const short8*)(wp + WN2) + wv * 8 * 64 + ln;

  f32x16 acc1 = (f32x16)(0.f);
  #pragma unroll 8
  for (int ks = 0; ks < 16; ++ks) {
    short8 A = nw1p[ks * 64];
    short8 B;
    if (ks < 8) {
      B = cvt8(gridf + (size_t)(n0 + l31) * HDIM + ks * 16 + hi * 8);
    } else {
      const float* ap = aggLDS + l31 * 129 + (ks - 8) * 16 + hi * 8;
      short8 t;
      #pragma unroll
      for (int i = 0; i < 8; ++i) t[i] = (short)f2bf_u(ap[i]);
      B = t;
    }
    acc1 = __builtin_amdgcn_mfma_f32_32x32x16_bf16(A, B, acc1, 0, 0, 0);
  }
  #pragma unroll
  for (int q = 0; q < 4; ++q) {
    #pragma unroll
    for (int m = 0; m < 2; ++m) {
      int r0 = q * 4 + m * 2;
      int col = 32 * wv + 8 * q + 4 * hi + 2 * m;
      float2 bb = *(const float2*)(nb1 + col);
      float x0 = acc1[r0] + bb.x, x1 = acc1[r0 + 1] + bb.y;
      x0 = x0 / (1.f + __expf(-x0));
      x1 = x1 / (1.f + __expf(-x1));
      *(u32*)(h1LDS + (l31 * 128 + (col ^ swzE))) = pack2bf(x0, x1);
    }
  }
  __syncthreads();

  f32x16 acc2 = (f32x16)(0.f);
  #pragma unroll
  for (int ks = 0; ks < 8; ++ks) {
    short8 A = nw2p[ks * 64];
    short8 B = *(const short8*)(h1LDS + l31 * 128 + ((ks * 16 + hi * 8) ^ swzE));
    acc2 = __builtin_amdgcn_mfma_f32_32x32x16_bf16(A, B, acc2, 0, 0, 0);
  }
  float vs = 0.f, vq = 0.f;
  #pragma unroll
  for (int r = 0; r < 16; ++r) {
    int col = 32 * wv + (r & 3) + 8 * (r >> 2) + 4 * hi;
    float x = acc2[r] + nb2[col];
    acc2[r] = x; vs += x; vq += x * x;
  }
  vs += __shfl_xor(vs, 32); vq += __shfl_xor(vq, 32);
  if (ln < 32) { statsLDS[wv][l31][0] = vs; statsLDS[wv][l31][1] = vq; }
  __syncthreads();
  float vsT = 0.f, vqT = 0.f;
  #pragma unroll
  for (int w2 = 0; w2 < 4; ++w2) { vsT += statsLDS[w2][l31][0]; vqT += statsLDS[w2][l31][1]; }
  float mean = vsT * (1.f / 128.f);
  float rstd = rsqrtf(vqT * (1.f / 128.f) - mean * mean + 1e-5f);
  #pragma unroll
  for (int r = 0; r < 16; ++r) {
    int col = 32 * wv + (r & 3) + 8 * (r >> 2) + 4 * hi;
    size_t idx = (size_t)(n0 + l31) * HDIM + col;
    out[idx] = (acc2[r] - mean) * rstd * nlng[col] + nlnb[col] + gridf[idx];
  }
}

extern "C" void kernel_launch(void* const* d_in, const int* in_sizes, int n_in,
                              void* d_out, int out_size, void* d_ws, size_t ws_size,
                              hipStream_t stream)
{
  (void)in_sizes; (void)n_in; (void)out_size; (void)ws_size;
  const float* ef   = (const float*)d_in[0];
  const float* grid = (const float*)d_in[1];
  const float* mesh = (const float*)d_in[2];
  const float* eW1  = (const float*)d_in[3];
  const float* eb1  = (const float*)d_in[4];
  const float* eW2  = (const float*)d_in[5];
  const float* eb2  = (const float*)d_in[6];
  const float* elng = (const float*)d_in[7];
  const float* elnb = (const float*)d_in[8];
  const float* nW1  = (const float*)d_in[9];
  const float* nb1  = (const float*)d_in[10];
  const float* nW2  = (const float*)d_in[11];
  const float* nb2  = (const float*)d_in[12];
  const float* nlng = (const float*)d_in[13];
  const float* nlnb = (const float*)d_in[14];
  const int* src    = (const int*)d_in[15];
  const int* dst    = (const int*)d_in[16];
  float* out = (float*)d_out;

  unsigned char* wsb = (unsigned char*)d_ws;
  u32* cnt  = (u32*)(wsb + WS_COUNT);
  u32* rp   = (u32*)(wsb + WS_ROWPTR);
  u32* wloc = (u32*)(wsb + WS_WLOC);
  u32* bsum = (u32*)(wsb + WS_BSUM);
  u64* sorted = (u64*)(wsb + WS_SORTED);
  unsigned short* wp = (unsigned short*)(wsb + WS_WEIGHTS);

  hipMemsetAsync(cnt, 0, (size_t)NGRID * 4, stream);
  pack_weights<<<448, 256, 0, stream>>>(eW1, eW2, nW1, nW2, wp);
  hist_k<<<NEDGE / 256, 256, 0, stream>>>(dst, cnt);
  scan1<<<256, 256, 0, stream>>>(cnt, rp, bsum);
  scan2<<<1, 256, 0, stream>>>(bsum);
  scan3<<<256, 256, 0, stream>>>(rp, wloc, bsum);
  scatter_k<<<NEDGE / 256, 256, 0, stream>>>(src, dst, wloc, sorted);
  fused_kernel<<<NGRID / 32, 256, 0, stream>>>(ef, grid, mesh, wp,
      eb1, eb2, elng, elnb, nb1, nb2, nlng, nlnb, rp, sorted, out);
}